// Round 7
// baseline (43.188 us; speedup 1.0000x reference)
//
#include <hip/hip_runtime.h>
#include <math.h>

#define NCOL 8192
#define BT   256
#define EPT  32

// exact double constants
#define MZM_LOSS_D 0.8912509381337456   // 10^-0.05
#define YB_LOSS_D  0.9332543007969910   // 10^-0.03
#define MRR_LOSS_D 0.8912509381337456   // 10^-0.05

static __device__ __forceinline__ void lds_barrier() {
    // drain LDS writes only; global loads may stay in flight across barrier
    asm volatile("s_waitcnt lgkmcnt(0)" ::: "memory");
    __builtin_amdgcn_s_barrier();
}

// Markstein: q = rint(f32div(a, inorm) * 255), exact IEEE f32 division
#define QF(dst, a_) do {                                   \
    const float a__  = (a_);                               \
    const float q0__ = a__ * y;                            \
    const float r__  = fmaf(-inorm, q0__, a__);            \
    (dst) = rintf(fmaf(r__, y, q0__) * 255.f);             \
} while (0)

__global__ __launch_bounds__(BT, 4)
void odp_main(const float* __restrict__ x, const float* __restrict__ w,
              const float* __restrict__ ntp, const float* __restrict__ nsp,
              const float* __restrict__ ntn, const float* __restrict__ nsn,
              float* __restrict__ out)
{
    __shared__ float  redX[4];
    __shared__ float  redW[4];
    __shared__ float  redT[4];
    __shared__ double redD[4];
    __shared__ double corrd[4];   // cD(t0), cT(t0), cD(tLast), cT(tLast)

    const int t    = threadIdx.x;
    const int lane = t & 63;
    const int wid  = t >> 6;
    const int b    = blockIdx.x;

    const float v_ntp = ntp[b], v_nsp = nsp[b], v_ntn = ntn[b], v_nsn = nsn[b];

    const float*  __restrict__ xrow = x + (size_t)b * NCOL;
    const float4* __restrict__ xr4  = (const float4*)xrow;
    const float4* __restrict__ w4   = (const float4*)w;

    // ---- issue ALL loads up front: 8 x-float4, 2 halo float2, 8 w-float4 ----
    float xf[EPT], wf[EPT];
    float mx = 0.f, mw = 0.f;
#pragma unroll
    for (int j = 0; j < 8; ++j) {
        const float4 xv = xr4[t * 8 + j];
        xf[4*j+0]=xv.x; xf[4*j+1]=xv.y; xf[4*j+2]=xv.z; xf[4*j+3]=xv.w;
        mx = fmaxf(mx, fmaxf(fmaxf(fabsf(xv.x), fabsf(xv.y)),
                             fmaxf(fabsf(xv.z), fabsf(xv.w))));
    }
    const float2 hxL = *(const float2*)(xrow + ((t > 0)      ? t*EPT - 2   : 0));
    const float2 hxR = *(const float2*)(xrow + ((t < BT - 1) ? t*EPT + EPT : NCOL - 2));
#pragma unroll
    for (int j = 0; j < 8; ++j) {
        const float4 wv = w4[t * 8 + j];
        wf[4*j+0]=wv.x; wf[4*j+1]=wv.y; wf[4*j+2]=wv.z; wf[4*j+3]=wv.w;
        mw = fmaxf(mw, fmaxf(fmaxf(fabsf(wv.x), fabsf(wv.y)),
                             fmaxf(fabsf(wv.z), fabsf(wv.w))));
    }

    // ---- wave + block max|x| (w-loads ride through the barrier) ----
#pragma unroll
    for (int off = 32; off; off >>= 1)
        mx = fmaxf(mx, __shfl_down(mx, off));
    if (lane == 0) redX[wid] = mx;
    lds_barrier();

    float inorm = fmaxf(fmaxf(redX[0], redX[1]), fmaxf(redX[2], redX[3]));
    inorm = (inorm <= 1e-9f) ? 1.f : inorm;
    const double inv_d = 1.0 / (double)inorm;   // correctly-rounded f32 recip seed
    const float  y     = (float)inv_d;

    // ---- quantize + conv + accumulate, two halves of 16, Q reused ----
    float Dv[4] = {0.f,0.f,0.f,0.f}, Tv[4] = {0.f,0.f,0.f,0.f};
    double cD = 0.0, cT = 0.0;
    const double DE0 = -((double)0.01f + (double)0.0025f);  // elems 0, N-1
    const double DE1 = -((double)0.0025f);                  // elems 1, N-2

#define HALF_BODY(H) do {                                                     \
    float Q[20];                                                              \
    if ((H) == 0) {                                                           \
        QF(Q[0], fabsf(hxL.x)); QF(Q[1], fabsf(hxL.y));                       \
        if (t == 0) { Q[0] = 0.f; Q[1] = 0.f; }                               \
    } else {                                                                  \
        QF(Q[0], fabsf(xf[14])); QF(Q[1], fabsf(xf[15]));                     \
    }                                                                         \
    _Pragma("unroll")                                                         \
    for (int cc = 0; cc < 16; ++cc) QF(Q[cc + 2], fabsf(xf[(H)*16 + cc]));    \
    if ((H) == 0) {                                                           \
        QF(Q[18], fabsf(xf[16])); QF(Q[19], fabsf(xf[17]));                   \
    } else {                                                                  \
        QF(Q[18], fabsf(hxR.x)); QF(Q[19], fabsf(hxR.y));                     \
        if (t == BT - 1) { Q[18] = 0.f; Q[19] = 0.f; }                        \
    }                                                                         \
    _Pragma("unroll")                                                         \
    for (int cc = 0; cc < 16; ++cc) {                                         \
        const int idx = (H)*16 + cc;                                          \
        const float s1 = Q[cc + 1] + Q[cc + 3];                               \
        const float s2 = Q[cc]     + Q[cc + 4];                               \
        float cv = fmaf(0.01f, s1, Q[cc + 2]);                                \
        cv = fmaf(0.0025f, s2, cv);                                           \
        const float sel = (xf[idx] > 0.f) ? wf[idx] : -wf[idx];               \
        Dv[cc & 3] = fmaf(cv, sel,        Dv[cc & 3]);                        \
        Tv[cc & 3] = fmaf(cv, fabsf(sel), Tv[cc & 3]);                        \
        if ((H) == 0 && t == 0 && cc < 2) {                                   \
            const double de = (cc == 0) ? DE0 : DE1;                          \
            cD += de * (double)(cv * sel);                                    \
            cT += de * (double)(cv * fabsf(sel));                             \
        }                                                                     \
        if ((H) == 1 && t == BT - 1 && cc >= 14) {                            \
            const double de = (cc == 15) ? DE0 : DE1;                         \
            cD += de * (double)(cv * sel);                                    \
            cT += de * (double)(cv * fabsf(sel));                             \
        }                                                                     \
    }                                                                         \
} while (0)

    HALF_BODY(0);
    HALF_BODY(1);

    double accD = ((double)Dv[0] + (double)Dv[1]) + ((double)Dv[2] + (double)Dv[3]);
    float  accT = (Tv[0] + Tv[1]) + (Tv[2] + Tv[3]);

    // ---- single end reduce: D (f64), T (f32), max|w| (f32) ----
#pragma unroll
    for (int off = 32; off; off >>= 1) {
        accD += __shfl_down(accD, off);
        accT += __shfl_down(accT, off);
        mw    = fmaxf(mw, __shfl_down(mw, off));
    }
    if (lane == 0)   { redD[wid] = accD; redT[wid] = accT; redW[wid] = mw; }
    if (t == 0)      { corrd[0] = cD; corrd[1] = cT; }
    if (t == BT - 1) { corrd[2] = cD; corrd[3] = cT; }
    lds_barrier();

    if (t == 0) {
        double D = 0.0, T = 0.0;
        float wnorm = redW[0];
#pragma unroll
        for (int i = 0; i < 4; ++i) {
            D += redD[i]; T += (double)redT[i];
            wnorm = fmaxf(wnorm, redW[i]);
        }
        wnorm = (wnorm <= 1e-9f) ? 1.f : wnorm;

        const double E_MID = 1.0 + 2.0 * (double)0.01f + 2.0 * (double)0.0025f;
        D = D * E_MID + (corrd[0] + corrd[2]);
        T = T * E_MID + (corrd[1] + corrd[3]);

        const double Kd = (10.0 / 255.0) * (YB_LOSS_D * MZM_LOSS_D) / (double)wnorm;
        const double ps = (T + D) * 0.5 * Kd * MRR_LOSS_D;
        const double ns = (T - D) * 0.5 * Kd * MRR_LOSS_D;

        const float thermal_f = 3.3135576e-12f;   // f32(4*kB*T*Hz/R)
        const float shot_f    = 3.204353268e-9f;  // f32(2*qE*Hz)

        double tp_ = ps + 1e-12 + (double)(v_ntp * thermal_f);
        tp_ *= (double)(1.0f + v_nsp * shot_f);   // == *1.0 in f32, faithful
        double tn_ = ns + 1e-12 + (double)(v_ntn * thermal_f);
        tn_ *= (double)(1.0f + v_nsn * shot_f);

        const double cur = tp_ - tn_;
        double v = fabs(cur * 100.0);
        v = fmin(v, 1.0);
        const double va  = rint(v * 255.0) * (1.0 / 255.0);
        const double sgn = (cur >= 0.0) ? 1.0 : -1.0;
        const double scale = (double)wnorm /
            (10.0 * 100.0 * MRR_LOSS_D * YB_LOSS_D * MZM_LOSS_D);
        out[b] = (float)(va * sgn * scale * (double)inorm);
    }
}

extern "C" void kernel_launch(void* const* d_in, const int* in_sizes, int n_in,
                              void* d_out, int out_size, void* d_ws, size_t ws_size,
                              hipStream_t stream) {
    const float* x   = (const float*)d_in[0];
    const float* w   = (const float*)d_in[1];
    const float* ntp = (const float*)d_in[2];
    const float* nsp = (const float*)d_in[3];
    const float* ntn = (const float*)d_in[4];
    const float* nsn = (const float*)d_in[5];
    float* out = (float*)d_out;
    odp_main<<<dim3(out_size), dim3(BT), 0, stream>>>(x, w, ntp, nsp, ntn, nsn, out);
}

// Round 8
// 31.713 us; speedup vs baseline: 1.3618x; 1.3618x over previous
//
#include <hip/hip_runtime.h>
#include <math.h>

#define NCOL 8192
#define BT   256
#define NF4  (NCOL / 4)   // 2048 float4 per row

// exact double constants
#define MZM_LOSS_D 0.8912509381337456   // 10^-0.05
#define YB_LOSS_D  0.9332543007969910   // 10^-0.03
#define MRR_LOSS_D 0.8912509381337456   // 10^-0.05

static __device__ __forceinline__ void lds_barrier() {
    // drain LDS ops only; global loads may stay in flight across barrier
    asm volatile("s_waitcnt lgkmcnt(0)" ::: "memory");
    __builtin_amdgcn_s_barrier();
}

// Markstein: q = rint(f32div(a, inorm) * 255), exact IEEE f32 division
#define QF(dst, a_) do {                                   \
    const float a__  = (a_);                               \
    const float q0__ = a__ * y;                            \
    const float r__  = fmaf(-inorm, q0__, a__);            \
    (dst) = rintf(fmaf(r__, y, q0__) * 255.f);             \
} while (0)

__global__ __launch_bounds__(BT, 4)
void odp_main(const float* __restrict__ x, const float* __restrict__ w,
              const float* __restrict__ ntp, const float* __restrict__ nsp,
              const float* __restrict__ ntn, const float* __restrict__ nsn,
              float* __restrict__ out)
{
    // x row staged in LDS, float4-granular XOR swizzle within 128B rows:
    // sf(g) = (g&~7) | ((g&7) ^ ((g>>3)&7))  -- bijective, keeps b128 contiguous
    __shared__ float4 xs4[NF4];
    __shared__ float  redX[4];
    __shared__ float  redW[4];
    __shared__ float  redT[4];
    __shared__ double redD[4];
    __shared__ double corrd[4];   // cD(t0), cT(t0), cD(tLast), cT(tLast)

    const int t    = threadIdx.x;
    const int lane = t & 63;
    const int wid  = t >> 6;
    const int b    = blockIdx.x;

    const float v_ntp = ntp[b], v_nsp = nsp[b], v_ntn = ntn[b], v_nsn = nsn[b];

    const float4* __restrict__ xr4 = (const float4*)(x + (size_t)b * NCOL);
    const float4* __restrict__ w4  = (const float4*)w;

    // ---- phase 1: x -> LDS (swizzled) + max|x|; w -> regs (per-thread contig) ----
    float mx = 0.f, mw = 0.f;
#pragma unroll
    for (int j = 0; j < 8; ++j) {
        const int g = t + BT * j;                 // lane-contiguous float4 index
        const float4 xv = xr4[g];
        mx = fmaxf(mx, fmaxf(fmaxf(fabsf(xv.x), fabsf(xv.y)),
                             fmaxf(fabsf(xv.z), fabsf(xv.w))));
        xs4[(g & ~7) | ((g & 7) ^ ((g >> 3) & 7))] = xv;
    }
    float4 wv[8];
#pragma unroll
    for (int j = 0; j < 8; ++j) {
        wv[j] = w4[8 * t + j];                    // w[32t .. 32t+32), L2-hot
        mw = fmaxf(mw, fmaxf(fmaxf(fabsf(wv[j].x), fabsf(wv[j].y)),
                             fmaxf(fabsf(wv[j].z), fabsf(wv[j].w))));
    }

#pragma unroll
    for (int off = 32; off; off >>= 1)
        mx = fmaxf(mx, __shfl_down(mx, off));
    if (lane == 0) redX[wid] = mx;
    lds_barrier();

    float inorm = fmaxf(fmaxf(redX[0], redX[1]), fmaxf(redX[2], redX[3]));
    inorm = (inorm <= 1e-9f) ? 1.f : inorm;
    const double inv_d = 1.0 / (double)inorm;   // correctly-rounded f32 recip seed
    const float  y     = (float)inv_d;

    // ---- phase 2: read own 36-float window from LDS, quantize ----
    float Q[36];            // Q[c+2] <-> elem 32t+c ; halos Q[0,1], Q[34,35]
    unsigned smask = 0;     // sign(x) bits for own 32 elems
#pragma unroll
    for (int k = 0; k < 8; ++k) {
        const float4 xq = xs4[8 * t + (k ^ (t & 7))];
        smask |= ((xq.x > 0.f) ? 1u : 0u) << (4 * k + 0);
        smask |= ((xq.y > 0.f) ? 1u : 0u) << (4 * k + 1);
        smask |= ((xq.z > 0.f) ? 1u : 0u) << (4 * k + 2);
        smask |= ((xq.w > 0.f) ? 1u : 0u) << (4 * k + 3);
        QF(Q[4 * k + 2], fabsf(xq.x));
        QF(Q[4 * k + 3], fabsf(xq.y));
        QF(Q[4 * k + 4], fabsf(xq.z));
        QF(Q[4 * k + 5], fabsf(xq.w));
    }
    if (t > 0) {            // left halo: dwords 32t-2, 32t-1 (swizzled row t-1)
        const float2 hl = ((const float2*)xs4)
            [16 * (t - 1) + ((30 ^ (((t - 1) & 7) << 2)) >> 1)];
        QF(Q[0], fabsf(hl.x));
        QF(Q[1], fabsf(hl.y));
    } else { Q[0] = 0.f; Q[1] = 0.f; }
    if (t < BT - 1) {       // right halo: dwords 32t+32, 32t+33 (swizzled row t+1)
        const float2 hr = ((const float2*)xs4)
            [16 * (t + 1) + (((t + 1) & 7) << 1)];
        QF(Q[34], fabsf(hr.x));
        QF(Q[35], fabsf(hr.y));
    } else { Q[34] = 0.f; Q[35] = 0.f; }

    // ---- conv + D/T accumulate (4 rotating f32 chains) ----
    float wf[32];
#pragma unroll
    for (int j = 0; j < 8; ++j) {
        wf[4*j+0] = wv[j].x; wf[4*j+1] = wv[j].y;
        wf[4*j+2] = wv[j].z; wf[4*j+3] = wv[j].w;
    }

    float Dv[4] = {0.f,0.f,0.f,0.f}, Tv[4] = {0.f,0.f,0.f,0.f};
    double cD = 0.0, cT = 0.0;
    const double DE0 = -((double)0.01f + (double)0.0025f);  // elems 0, N-1
    const double DE1 = -((double)0.0025f);                  // elems 1, N-2

#pragma unroll
    for (int c = 0; c < 32; ++c) {
        const float s1 = Q[c + 1] + Q[c + 3];
        const float s2 = Q[c]     + Q[c + 4];
        float cv = fmaf(0.01f, s1, Q[c + 2]);
        cv = fmaf(0.0025f, s2, cv);
        const float sel = ((smask >> c) & 1u) ? wf[c] : -wf[c];
        Dv[c & 3] = fmaf(cv, sel,        Dv[c & 3]);
        Tv[c & 3] = fmaf(cv, fabsf(sel), Tv[c & 3]);
        if (t == 0 && c < 2) {
            const double de = (c == 0) ? DE0 : DE1;
            cD += de * (double)(cv * sel);
            cT += de * (double)(cv * fabsf(sel));
        }
        if (t == BT - 1 && c >= 30) {
            const double de = (c == 31) ? DE0 : DE1;
            cD += de * (double)(cv * sel);
            cT += de * (double)(cv * fabsf(sel));
        }
    }

    double accD = ((double)Dv[0] + (double)Dv[1]) + ((double)Dv[2] + (double)Dv[3]);
    float  accT = (Tv[0] + Tv[1]) + (Tv[2] + Tv[3]);

    // ---- single end reduce: D (f64), T (f32), max|w| (f32) ----
#pragma unroll
    for (int off = 32; off; off >>= 1) {
        accD += __shfl_down(accD, off);
        accT += __shfl_down(accT, off);
        mw    = fmaxf(mw, __shfl_down(mw, off));
    }
    if (lane == 0)   { redD[wid] = accD; redT[wid] = accT; redW[wid] = mw; }
    if (t == 0)      { corrd[0] = cD; corrd[1] = cT; }
    if (t == BT - 1) { corrd[2] = cD; corrd[3] = cT; }
    lds_barrier();

    if (t == 0) {
        double D = 0.0, T = 0.0;
        float wnorm = redW[0];
#pragma unroll
        for (int i = 0; i < 4; ++i) {
            D += redD[i]; T += (double)redT[i];
            wnorm = fmaxf(wnorm, redW[i]);
        }
        wnorm = (wnorm <= 1e-9f) ? 1.f : wnorm;

        const double E_MID = 1.0 + 2.0 * (double)0.01f + 2.0 * (double)0.0025f;
        D = D * E_MID + (corrd[0] + corrd[2]);
        T = T * E_MID + (corrd[1] + corrd[3]);

        const double Kd = (10.0 / 255.0) * (YB_LOSS_D * MZM_LOSS_D) / (double)wnorm;
        const double ps = (T + D) * 0.5 * Kd * MRR_LOSS_D;
        const double ns = (T - D) * 0.5 * Kd * MRR_LOSS_D;

        const float thermal_f = 3.3135576e-12f;   // f32(4*kB*T*Hz/R)
        const float shot_f    = 3.204353268e-9f;  // f32(2*qE*Hz)

        double tp_ = ps + 1e-12 + (double)(v_ntp * thermal_f);
        tp_ *= (double)(1.0f + v_nsp * shot_f);   // == *1.0 in f32, faithful
        double tn_ = ns + 1e-12 + (double)(v_ntn * thermal_f);
        tn_ *= (double)(1.0f + v_nsn * shot_f);

        const double cur = tp_ - tn_;
        double v = fabs(cur * 100.0);
        v = fmin(v, 1.0);
        const double va  = rint(v * 255.0) * (1.0 / 255.0);
        const double sgn = (cur >= 0.0) ? 1.0 : -1.0;
        const double scale = (double)wnorm /
            (10.0 * 100.0 * MRR_LOSS_D * YB_LOSS_D * MZM_LOSS_D);
        out[b] = (float)(va * sgn * scale * (double)inorm);
    }
}

extern "C" void kernel_launch(void* const* d_in, const int* in_sizes, int n_in,
                              void* d_out, int out_size, void* d_ws, size_t ws_size,
                              hipStream_t stream) {
    const float* x   = (const float*)d_in[0];
    const float* w   = (const float*)d_in[1];
    const float* ntp = (const float*)d_in[2];
    const float* nsp = (const float*)d_in[3];
    const float* ntn = (const float*)d_in[4];
    const float* nsn = (const float*)d_in[5];
    float* out = (float*)d_out;
    odp_main<<<dim3(out_size), dim3(BT), 0, stream>>>(x, w, ntp, nsp, ntn, nsn, out);
}